// Round 7
// baseline (76.879 us; speedup 1.0000x reference)
//
#include <hip/hip_runtime.h>
#include <hip/hip_bf16.h>

#define EPS 1e-5f

typedef unsigned short u16;
typedef __attribute__((ext_vector_type(8))) __bf16 bf16x8;
typedef __attribute__((ext_vector_type(4))) float f32x4;
typedef __attribute__((ext_vector_type(4))) unsigned short u16x4;

// round-to-nearest-even f32 -> bf16
__device__ __forceinline__ u16 f2bf(float f) {
  unsigned int u = __float_as_uint(f);
  u += 0x7fffu + ((u >> 16) & 1u);
  return (u16)(u >> 16);
}

// ---------------------------------------------------------------------------
// prep0: blocks 0..15 -> transpose W0 into k-blocked col-major f32:
//          W0Tq[k>>2][u][k&3] = gW[u][k]   (prep1 reads lane-coalesced 16B/u)
//        block 16    -> zero S (atomic accumulator for rn_main)
// Must be a separate kernel from prep1: prep1's L/R blocks consume W0Tq and
// inter-block ordering within one launch is undefined.
// ---------------------------------------------------------------------------
__global__ __launch_bounds__(256) void prep0(const float* __restrict__ gW,
                                             float* __restrict__ W0Tq,
                                             float* __restrict__ S) {
  const int t = threadIdx.x;
  const int blk = blockIdx.x;
  if (blk >= 16) {
    float4 z = {0.f, 0.f, 0.f, 0.f};
    float4* s4 = (float4*)S;
    #pragma unroll
    for (int idx = 0; idx < 8; ++idx) s4[idx * 256 + t] = z;
    return;
  }
  const int u = blk * 16 + (t >> 4);
  const int c0 = (t & 15) * 16;
  const float* wrow = gW + (size_t)u * 256;
  #pragma unroll
  for (int c = 0; c < 16; ++c) {
    const int k = c0 + c;
    W0Tq[(((size_t)(k >> 2)) * 256 + u) * 4 + (k & 3)] = wrow[k];
  }
}

// ---------------------------------------------------------------------------
// prep1 (one launch, 328 independent blocks):
//   blocks   0..255 -> L/R projections (layer-0 fold), 8 objects each,
//                      weights read COALESCED from W0Tq (16B/lane bursts)
//   blocks 256..287 -> fold BN into G layers 1,2, FRAGMENT-MAJOR bf16:
//       Wf[l][kk][cb][lane=g*16+r][e] = W_folded[u=cb*16+r][k=kk*32+g*8+e]
//   blocks 288..319 -> fold BN into F layers 0,1, K-BLOCKED col-major f32
//   blocks 320..327 -> final layer: foWt[k>>2][u][k&3] = foW[u][k]
// ---------------------------------------------------------------------------
__global__ __launch_bounds__(256) void prep1(
    const float* __restrict__ x, const float* __restrict__ W0Tq,
    const float* __restrict__ gW,
    const float* __restrict__ gb, const float* __restrict__ ggamma,
    const float* __restrict__ gbeta, const float* __restrict__ gmean,
    const float* __restrict__ gvar,
    const float* __restrict__ fW, const float* __restrict__ fb,
    const float* __restrict__ fgamma, const float* __restrict__ fbeta,
    const float* __restrict__ fmean, const float* __restrict__ fvar,
    const float* __restrict__ foW,
    u16* __restrict__ Wf, float* __restrict__ biasOut,
    float* __restrict__ fWt, float* __restrict__ fbias,
    float* __restrict__ foWt,
    float* __restrict__ Lf, float* __restrict__ Rf) {
  const int t = threadIdx.x;
  const int blk = blockIdx.x;

  if (blk >= 320) {
    // ---- foW k-blocked transpose: 8 blocks, 16 rows (u) each
    const int row = (blk - 320) * 16 + (t >> 4);
    const int c0 = (t & 15) * 16;
    const float* wrow = foW + (size_t)row * 256;
    #pragma unroll
    for (int c = 0; c < 16; ++c) {
      const int k = c0 + c;
      foWt[(((size_t)(k >> 2) * 128) + row) * 4 + (k & 3)] = wrow[k];
    }
    return;
  }
  if (blk >= 288) {
    // ---- F fold: 32 blocks, 16 rows (u) of one layer each
    const int idx = blk - 288;
    const int l = idx >> 4;
    const int row = (idx & 15) * 16 + (t >> 4);
    const int c0 = (t & 15) * 16;
    const int fi = l * 256 + row;
    const float s = fgamma[fi] * rsqrtf(fvar[fi] + EPS);
    if (c0 == 0) fbias[l * 256 + row] = (fb[fi] - fmean[fi]) * s + fbeta[fi];
    const float* wrow = fW + (size_t)fi * 256;
    #pragma unroll
    for (int c = 0; c < 16; ++c) {
      const int k = c0 + c;
      fWt[(((size_t)l * 64 + (k >> 2)) * 256 + row) * 4 + (k & 3)] =
          wrow[k] * s;
    }
    return;
  }
  if (blk >= 256) {
    // ---- G fold: 32 blocks, 16 rows (u) of one layer each
    const int idx = blk - 256;
    const int l = idx >> 4;                 // 0,1 -> g layer 1,2
    const int gl = l + 1;
    const int row = (idx & 15) * 16 + (t >> 4);
    const int c0 = (t & 15) * 16;
    const int gi = gl * 256 + row;
    const float s = ggamma[gi] * rsqrtf(gvar[gi] + EPS);
    if (c0 == 0) biasOut[l * 256 + row] = (gb[gi] - gmean[gi]) * s + gbeta[gi];
    const float* wrow = gW + (size_t)gi * 256;
    const int r = row & 15;
    const int cb = row >> 4;
    #pragma unroll
    for (int c = 0; c < 16; ++c) {
      const int k = c0 + c;
      const int kk = k >> 5;
      const int g = (k >> 3) & 3;
      const int e = k & 7;
      const size_t flat =
          (((((size_t)l * 8 + kk) * 16 + cb) * 64) + g * 16 + r) * 8 + e;
      Wf[flat] = f2bf(wrow[k] * s);
    }
    return;
  }
  // ---- L/R part: 256 blocks = 32 batches x 8 chunks of 8 objects
  const int b = blk >> 3;
  const int chunk = blk & 7;
  __shared__ __align__(16) float4 xs4[8][32];   // 8 obj x 128 dims
  {
    const float4* src = (const float4*)(x + ((size_t)b * 64 + chunk * 8) * 128);
    ((float4*)xs4)[t] = src[t];
  }
  __syncthreads();
  const int u = t;
  float accL[8], accR[8];
  #pragma unroll
  for (int nn = 0; nn < 8; ++nn) { accL[nn] = 0.f; accR[nn] = 0.f; }
  const float4* wq = (const float4*)W0Tq;       // [kq][u] 16B, coalesced on u
  for (int kq = 0; kq < 32; ++kq) {
    const float4 a = wq[(size_t)kq * 256 + u];        // W0 left, k=4kq..+3
    const float4 c = wq[(size_t)(kq + 32) * 256 + u]; // W0 right
    #pragma unroll
    for (int nn = 0; nn < 8; ++nn) {
      const float4 xv = xs4[nn][kq];
      accL[nn] += a.x * xv.x + a.y * xv.y + a.z * xv.z + a.w * xv.w;
      accR[nn] += c.x * xv.x + c.y * xv.y + c.z * xv.z + c.w * xv.w;
    }
  }
  const float s = ggamma[u] * rsqrtf(gvar[u] + EPS);
  const float lb = (gb[u] - gmean[u]) * s + gbeta[u];
  const int n0 = chunk * 8;
  #pragma unroll
  for (int nn = 0; nn < 8; ++nn) {
    Lf[((size_t)b * 64 + n0 + nn) * 256 + u] = accL[nn] * s + lb;
    Rf[((size_t)b * 64 + n0 + nn) * 256 + u] = accR[nn] * s;
  }
}

// ---------------------------------------------------------------------------
// Main fused kernel: per (ig, b): TWO i-values, 128 pair-rows.
//   h  = relu(L_i + R_j)   -> LDS bf16 (XOR-swizzled), 128 rows, 64 KiB
//   h' = relu(W1 h + b1)   -> same LDS buffer.  Layer A uses SWAPPED MFMA
//        operands (A=W1, B=h) so D = [u-rows x pair-cols]: each lane holds 4
//        CONSECUTIVE u for one pair -> h' writes pack into ds_write_b64
//        (32 instead of 128 LDS writes/thread). Stored h'[pair][u] bytes are
//        identical to the old layout, so layer B is unchanged.
//   out = relu(W2 h' + b2) -> column sums -> atomicAdd into S[b] (S zeroed
//        by prep0; each col touched by exactly one wave per block).
// __launch_bounds__(256,2): cap 256 total regs (VGPR+AGPR unified) -> no
// spill (acc alone is 128 AGPR). LDS 64 KiB -> 2 blocks/CU.
// ---------------------------------------------------------------------------
__global__ __launch_bounds__(256, 2) void rn_main(
    const float* __restrict__ Lf, const float* __restrict__ Rf,
    const u16* __restrict__ Wf, const float* __restrict__ biasg,
    float* __restrict__ S) {
  __shared__ __align__(16) u16 hbuf[128 * 256];   // 64 KiB, reused per layer
  char* hb = (char*)hbuf;
  const int b = blockIdx.y;
  const int ig = blockIdx.x;             // i-group of 2
  const int t = threadIdx.x;
  const int wave = t >> 6;
  const int lane = t & 63;
  const int g = lane >> 4;
  const int r = lane & 15;

  // ---- Phase 0: rows p = it*64+j; h[p][c] = relu(L[2ig+it][c] + R[j][c])
  {
    const float4 lv0 =
        *(const float4*)(Lf + ((size_t)b * 64 + ig * 2) * 256 + lane * 4);
    const float4 lv1 =
        *(const float4*)(Lf + ((size_t)b * 64 + ig * 2 + 1) * 256 + lane * 4);
    const float4* rbase = (const float4*)(Rf + (size_t)b * 64 * 256);
    #pragma unroll
    for (int q = 0; q < 32; ++q) {
      const int p = q * 4 + wave;
      const int j = p & 63;
      const float4 rv = rbase[(size_t)j * 64 + lane];
      const float4 lv = (q < 16) ? lv0 : lv1;
      u16x4 pk;
      pk[0] = f2bf(fmaxf(lv.x + rv.x, 0.f));
      pk[1] = f2bf(fmaxf(lv.y + rv.y, 0.f));
      pk[2] = f2bf(fmaxf(lv.z + rv.z, 0.f));
      pk[3] = f2bf(fmaxf(lv.w + rv.w, 0.f));
      *(u16x4*)(hb + (p * 512 + ((lane * 8) ^ ((p & 7) << 4)))) = pk;
    }
  }
  __syncthreads();

  const f32x4 zero4 = {0.f, 0.f, 0.f, 0.f};

  // ---- Layer A (swapped operands): accA[mt=u-frag 0..3][nt=pair-frag 0..7]
  {
    f32x4 accA[4][8];
    #pragma unroll
    for (int mt = 0; mt < 4; ++mt)
      #pragma unroll
      for (int nt = 0; nt < 8; ++nt) accA[mt][nt] = zero4;
    const bf16x8* wb = (const bf16x8*)Wf;            // layer 0 fragments
    #pragma unroll
    for (int kk = 0; kk < 8; ++kk) {
      bf16x8 wfrag[4];
      #pragma unroll
      for (int mt = 0; mt < 4; ++mt)
        wfrag[mt] = wb[(kk * 16 + wave * 4 + mt) * 64 + lane];
      #pragma unroll
      for (int nt = 0; nt < 8; ++nt) {
        const int prow = nt * 16 + r;
        const bf16x8 hfrag = *(const bf16x8*)(
            hb + (prow * 512 + ((kk * 64 + g * 16) ^ ((r & 7) << 4))));
        #pragma unroll
        for (int mt = 0; mt < 4; ++mt)
          accA[mt][nt] = __builtin_amdgcn_mfma_f32_16x16x32_bf16(
              wfrag[mt], hfrag, accA[mt][nt], 0, 0, 0);
      }
    }
    __syncthreads();  // all reads of h done -> safe to overwrite

    // ---- h' = relu(accA + b1): lane holds u = wave*64+mt*16+g*4+reg,
    // pair = nt*16+r  ->  4 consecutive u -> one b64 write per fragment.
    float4 bias4[4];
    #pragma unroll
    for (int mt = 0; mt < 4; ++mt)
      bias4[mt] = *(const float4*)(biasg + wave * 64 + mt * 16 + g * 4);
    #pragma unroll
    for (int nt = 0; nt < 8; ++nt) {
      const int prow = nt * 16 + r;
      const int swz = (r & 7) << 4;
      #pragma unroll
      for (int mt = 0; mt < 4; ++mt) {
        u16x4 pk;
        pk[0] = f2bf(fmaxf(accA[mt][nt][0] + bias4[mt].x, 0.f));
        pk[1] = f2bf(fmaxf(accA[mt][nt][1] + bias4[mt].y, 0.f));
        pk[2] = f2bf(fmaxf(accA[mt][nt][2] + bias4[mt].z, 0.f));
        pk[3] = f2bf(fmaxf(accA[mt][nt][3] + bias4[mt].w, 0.f));
        const int cb = wave * 128 + mt * 32 + g * 8;
        *(u16x4*)(hb + (prow * 512 + (cb ^ swz))) = pk;
      }
    }
  }
  __syncthreads();

  // ---- Layer B (original operand order): h' -> relu -> column sums -> S
  {
    f32x4 acc[8][4];
    #pragma unroll
    for (int mt = 0; mt < 8; ++mt)
      #pragma unroll
      for (int nt = 0; nt < 4; ++nt) acc[mt][nt] = zero4;
    const bf16x8* wb = (const bf16x8*)(Wf + 65536);  // layer 1 fragments
    #pragma unroll
    for (int kk = 0; kk < 8; ++kk) {
      bf16x8 bfrag[4];
      #pragma unroll
      for (int nt = 0; nt < 4; ++nt)
        bfrag[nt] = wb[(kk * 16 + wave * 4 + nt) * 64 + lane];
      #pragma unroll
      for (int mt = 0; mt < 8; ++mt) {
        const int row = mt * 16 + r;
        const bf16x8 afrag = *(const bf16x8*)(
            hb + (row * 512 + ((kk * 64 + g * 16) ^ ((r & 7) << 4))));
        #pragma unroll
        for (int nt = 0; nt < 4; ++nt)
          acc[mt][nt] = __builtin_amdgcn_mfma_f32_16x16x32_bf16(
              afrag, bfrag[nt], acc[mt][nt], 0, 0, 0);
      }
    }
    #pragma unroll
    for (int nt = 0; nt < 4; ++nt) {
      const int col = wave * 64 + nt * 16 + r;
      const float bias = biasg[256 + col];
      float cs = 0.f;
      #pragma unroll
      for (int mt = 0; mt < 8; ++mt)
        #pragma unroll
        for (int reg = 0; reg < 4; ++reg)
          cs += fmaxf(acc[mt][nt][reg] + bias, 0.f);
      cs += __shfl_xor(cs, 16, 64);
      cs += __shfl_xor(cs, 32, 64);
      if (lane < 16) atomicAdd(&S[(size_t)b * 256 + col], cs);
    }
  }
}

// ---------------------------------------------------------------------------
// F head: per batch: read S[b], 2x(matvec+ReLU) + final 256->128, K-BLOCKED
// col-major weights (each lane loads float4 along k, coalesced).
// ---------------------------------------------------------------------------
__global__ __launch_bounds__(256) void head_kernel(
    const float* __restrict__ S, const float* __restrict__ fWt,
    const float* __restrict__ fbias, const float* __restrict__ foWt,
    const float* __restrict__ fob, float* __restrict__ out) {
  const int b = blockIdx.x;
  const int u = threadIdx.x;
  __shared__ __align__(16) float h[256];
  h[u] = S[(size_t)b * 256 + u];
  __syncthreads();
  #pragma unroll
  for (int l = 0; l < 2; ++l) {
    const float4* wc = (const float4*)fWt + ((size_t)l * 64) * 256 + u;
    float z = 0.f;
    #pragma unroll 8
    for (int k4 = 0; k4 < 64; ++k4) {
      const float4 wv = wc[(size_t)k4 * 256];
      const float4 hv = *((const float4*)&h[k4 * 4]);
      z += wv.x * hv.x + wv.y * hv.y + wv.z * hv.z + wv.w * hv.w;
    }
    z = fmaxf(z + fbias[l * 256 + u], 0.f);
    __syncthreads();
    h[u] = z;
    __syncthreads();
  }
  if (u < 128) {
    const float4* wc = (const float4*)foWt + u;
    float y = fob[u];
    #pragma unroll 8
    for (int k4 = 0; k4 < 64; ++k4) {
      const float4 wv = wc[(size_t)k4 * 128];
      const float4 hv = *((const float4*)&h[k4 * 4]);
      y += wv.x * hv.x + wv.y * hv.y + wv.z * hv.z + wv.w * hv.w;
    }
    out[(size_t)b * 128 + u] = y;
  }
}

extern "C" void kernel_launch(void* const* d_in, const int* in_sizes, int n_in,
                              void* d_out, int out_size, void* d_ws, size_t ws_size,
                              hipStream_t stream) {
  const float* x      = (const float*)d_in[0];
  const float* gW     = (const float*)d_in[1];
  const float* gb     = (const float*)d_in[2];
  const float* ggamma = (const float*)d_in[3];
  const float* gbeta  = (const float*)d_in[4];
  const float* gmean  = (const float*)d_in[5];
  const float* gvar   = (const float*)d_in[6];
  const float* fW     = (const float*)d_in[7];
  const float* fb     = (const float*)d_in[8];
  const float* fgamma = (const float*)d_in[9];
  const float* fbeta  = (const float*)d_in[10];
  const float* fmean  = (const float*)d_in[11];
  const float* fvar   = (const float*)d_in[12];
  const float* foW    = (const float*)d_in[13];
  const float* fob    = (const float*)d_in[14];

  // workspace layout
  u16* Wf = (u16*)d_ws;                    // 2*65536 bf16, fragment-major
  float* biasg = (float*)(Wf + 2 * 65536); // 512 f32
  float* fbias = biasg + 512;              // 512 f32
  float* fWt  = fbias + 512;               // 2*65536 f32, k-blocked col-major
  float* foWt = fWt + 2 * 65536;           // 256*128 f32, k-blocked col-major
  float* W0Tq = foWt + 256 * 128;          // 256*256 f32, k-blocked col-major
  float* S    = W0Tq + 256 * 256;          // 32*256 f32 (atomic accumulator)
  float* Lfp = S + 32 * 256;               // 32*64*256 f32
  float* Rfp = Lfp + 32 * 64 * 256;        // 32*64*256 f32

  prep0<<<dim3(17), 256, 0, stream>>>(gW, W0Tq, S);
  prep1<<<dim3(328), 256, 0, stream>>>(x, W0Tq, gW, gb, ggamma, gbeta, gmean,
                                       gvar, fW, fb, fgamma, fbeta, fmean,
                                       fvar, foW, Wf, biasg, fWt, fbias, foWt,
                                       Lfp, Rfp);
  rn_main<<<dim3(32, 32), 256, 0, stream>>>(Lfp, Rfp, Wf, biasg, S);
  head_kernel<<<dim3(32), 256, 0, stream>>>(S, fWt, fbias, foWt, fob,
                                            (float*)d_out);
}

// Round 8
// 74.757 us; speedup vs baseline: 1.0284x; 1.0284x over previous
//
#include <hip/hip_runtime.h>
#include <hip/hip_bf16.h>

#define EPS 1e-5f

typedef unsigned short u16;
typedef __attribute__((ext_vector_type(8))) __bf16 bf16x8;
typedef __attribute__((ext_vector_type(4))) float f32x4;
typedef __attribute__((ext_vector_type(4))) unsigned short u16x4;

// f32 -> bf16 RNE via the native conversion (compiler packs pairs into
// v_cvt_pk_bf16_f32; the old manual integer RNE was 3 VALU ops/element and
// unpackable -> ~2300 VALU inst/wave in rn_main).
__device__ __forceinline__ u16 f2bf(float f) {
  union { __hip_bfloat16 h; u16 u; } cv;
  cv.h = __float2bfloat16(f);
  return cv.u;
}

// ---------------------------------------------------------------------------
// prep0: 16 blocks -> transpose W0 into k-blocked col-major f32:
//          W0Tq[k>>2][u][k&3] = gW[u][k]   (prep1 reads lane-coalesced 16B/u)
// Separate kernel: prep1's L/R blocks consume W0Tq (inter-block ordering
// within one launch is undefined).
// ---------------------------------------------------------------------------
__global__ __launch_bounds__(256) void prep0(const float* __restrict__ gW,
                                             float* __restrict__ W0Tq) {
  const int t = threadIdx.x;
  const int u = blockIdx.x * 16 + (t >> 4);
  const int c0 = (t & 15) * 16;
  const float* wrow = gW + (size_t)u * 256;
  #pragma unroll
  for (int c = 0; c < 16; ++c) {
    const int k = c0 + c;
    W0Tq[(((size_t)(k >> 2)) * 256 + u) * 4 + (k & 3)] = wrow[k];
  }
}

// ---------------------------------------------------------------------------
// prep1 (one launch, 329 independent blocks):
//   blocks   0..255 -> L/R projections (layer-0 fold), 8 objects each,
//                      weights read COALESCED from W0Tq (16B/lane bursts)
//   blocks 256..287 -> fold BN into G layers 1,2, FRAGMENT-MAJOR bf16
//   blocks 288..319 -> fold BN into F layers 0,1, K-BLOCKED col-major f32
//   blocks 320..327 -> final layer: foWt[k>>2][u][k&3] = foW[u][k]
//   block  328      -> zero S (atomic accumulator consumed by rn_main)
// ---------------------------------------------------------------------------
__global__ __launch_bounds__(256) void prep1(
    const float* __restrict__ x, const float* __restrict__ W0Tq,
    const float* __restrict__ gW,
    const float* __restrict__ gb, const float* __restrict__ ggamma,
    const float* __restrict__ gbeta, const float* __restrict__ gmean,
    const float* __restrict__ gvar,
    const float* __restrict__ fW, const float* __restrict__ fb,
    const float* __restrict__ fgamma, const float* __restrict__ fbeta,
    const float* __restrict__ fmean, const float* __restrict__ fvar,
    const float* __restrict__ foW,
    u16* __restrict__ Wf, float* __restrict__ biasOut,
    float* __restrict__ fWt, float* __restrict__ fbias,
    float* __restrict__ foWt,
    float* __restrict__ Lf, float* __restrict__ Rf,
    float* __restrict__ S) {
  const int t = threadIdx.x;
  const int blk = blockIdx.x;

  if (blk >= 328) {
    // ---- zero S: 32*256 f32 = 2048 float4
    float4 z = {0.f, 0.f, 0.f, 0.f};
    float4* s4 = (float4*)S;
    #pragma unroll
    for (int idx = 0; idx < 8; ++idx) s4[idx * 256 + t] = z;
    return;
  }
  if (blk >= 320) {
    // ---- foW k-blocked transpose: 8 blocks, 16 rows (u) each
    const int row = (blk - 320) * 16 + (t >> 4);
    const int c0 = (t & 15) * 16;
    const float* wrow = foW + (size_t)row * 256;
    #pragma unroll
    for (int c = 0; c < 16; ++c) {
      const int k = c0 + c;
      foWt[(((size_t)(k >> 2) * 128) + row) * 4 + (k & 3)] = wrow[k];
    }
    return;
  }
  if (blk >= 288) {
    // ---- F fold: 32 blocks, 16 rows (u) of one layer each
    const int idx = blk - 288;
    const int l = idx >> 4;
    const int row = (idx & 15) * 16 + (t >> 4);
    const int c0 = (t & 15) * 16;
    const int fi = l * 256 + row;
    const float s = fgamma[fi] * rsqrtf(fvar[fi] + EPS);
    if (c0 == 0) fbias[l * 256 + row] = (fb[fi] - fmean[fi]) * s + fbeta[fi];
    const float* wrow = fW + (size_t)fi * 256;
    #pragma unroll
    for (int c = 0; c < 16; ++c) {
      const int k = c0 + c;
      fWt[(((size_t)l * 64 + (k >> 2)) * 256 + row) * 4 + (k & 3)] =
          wrow[k] * s;
    }
    return;
  }
  if (blk >= 256) {
    // ---- G fold: 32 blocks, 16 rows (u) of one layer each
    const int idx = blk - 256;
    const int l = idx >> 4;                 // 0,1 -> g layer 1,2
    const int gl = l + 1;
    const int row = (idx & 15) * 16 + (t >> 4);
    const int c0 = (t & 15) * 16;
    const int gi = gl * 256 + row;
    const float s = ggamma[gi] * rsqrtf(gvar[gi] + EPS);
    if (c0 == 0) biasOut[l * 256 + row] = (gb[gi] - gmean[gi]) * s + gbeta[gi];
    const float* wrow = gW + (size_t)gi * 256;
    const int r = row & 15;
    const int cb = row >> 4;
    #pragma unroll
    for (int c = 0; c < 16; ++c) {
      const int k = c0 + c;
      const int kk = k >> 5;
      const int g = (k >> 3) & 3;
      const int e = k & 7;
      const size_t flat =
          (((((size_t)l * 8 + kk) * 16 + cb) * 64) + g * 16 + r) * 8 + e;
      Wf[flat] = f2bf(wrow[k] * s);
    }
    return;
  }
  // ---- L/R part: 256 blocks = 32 batches x 8 chunks of 8 objects
  const int b = blk >> 3;
  const int chunk = blk & 7;
  __shared__ __align__(16) float4 xs4[8][32];   // 8 obj x 128 dims
  {
    const float4* src = (const float4*)(x + ((size_t)b * 64 + chunk * 8) * 128);
    ((float4*)xs4)[t] = src[t];
  }
  __syncthreads();
  const int u = t;
  float accL[8], accR[8];
  #pragma unroll
  for (int nn = 0; nn < 8; ++nn) { accL[nn] = 0.f; accR[nn] = 0.f; }
  const float4* wq = (const float4*)W0Tq;       // [kq][u] 16B, coalesced on u
  for (int kq = 0; kq < 32; ++kq) {
    const float4 a = wq[(size_t)kq * 256 + u];        // W0 left, k=4kq..+3
    const float4 c = wq[(size_t)(kq + 32) * 256 + u]; // W0 right
    #pragma unroll
    for (int nn = 0; nn < 8; ++nn) {
      const float4 xv = xs4[nn][kq];
      accL[nn] += a.x * xv.x + a.y * xv.y + a.z * xv.z + a.w * xv.w;
      accR[nn] += c.x * xv.x + c.y * xv.y + c.z * xv.z + c.w * xv.w;
    }
  }
  const float s = ggamma[u] * rsqrtf(gvar[u] + EPS);
  const float lb = (gb[u] - gmean[u]) * s + gbeta[u];
  const int n0 = chunk * 8;
  #pragma unroll
  for (int nn = 0; nn < 8; ++nn) {
    Lf[((size_t)b * 64 + n0 + nn) * 256 + u] = accL[nn] * s + lb;
    Rf[((size_t)b * 64 + n0 + nn) * 256 + u] = accR[nn] * s;
  }
}

// ---------------------------------------------------------------------------
// Main fused kernel: per (ig, b): TWO i-values, 128 pair-rows.
//   h  = relu(L_i + R_j)   -> LDS bf16 (XOR-swizzled), 128 rows, 64 KiB
//   h' = relu(W1 h + b1)   -> same LDS buffer (swapped MFMA operands so each
//        lane holds 4 consecutive u for one pair -> b64-packed LDS writes)
//   out = relu(W2 h' + b2) -> column sums -> atomicAdd into S[b]
// s_setprio(1) wraps both compute phases: each SIMD hosts 2 waves from
// DIFFERENT blocks (4-wave blocks spread over 4 SIMDs), so wave role
// diversity exists and priority arbitration can favor the MFMA-phase wave.
// __launch_bounds__(256,2): 256 total regs (VGPR+AGPR unified), no spill.
// ---------------------------------------------------------------------------
__global__ __launch_bounds__(256, 2) void rn_main(
    const float* __restrict__ Lf, const float* __restrict__ Rf,
    const u16* __restrict__ Wf, const float* __restrict__ biasg,
    float* __restrict__ S) {
  __shared__ __align__(16) u16 hbuf[128 * 256];   // 64 KiB, reused per layer
  char* hb = (char*)hbuf;
  const int b = blockIdx.y;
  const int ig = blockIdx.x;             // i-group of 2
  const int t = threadIdx.x;
  const int wave = t >> 6;
  const int lane = t & 63;
  const int g = lane >> 4;
  const int r = lane & 15;

  // ---- Phase 0: rows p = it*64+j; h[p][c] = relu(L[2ig+it][c] + R[j][c])
  {
    const float4 lv0 =
        *(const float4*)(Lf + ((size_t)b * 64 + ig * 2) * 256 + lane * 4);
    const float4 lv1 =
        *(const float4*)(Lf + ((size_t)b * 64 + ig * 2 + 1) * 256 + lane * 4);
    const float4* rbase = (const float4*)(Rf + (size_t)b * 64 * 256);
    #pragma unroll
    for (int q = 0; q < 32; ++q) {
      const int p = q * 4 + wave;
      const int j = p & 63;
      const float4 rv = rbase[(size_t)j * 64 + lane];
      const float4 lv = (q < 16) ? lv0 : lv1;
      u16x4 pk;
      pk[0] = f2bf(fmaxf(lv.x + rv.x, 0.f));
      pk[1] = f2bf(fmaxf(lv.y + rv.y, 0.f));
      pk[2] = f2bf(fmaxf(lv.z + rv.z, 0.f));
      pk[3] = f2bf(fmaxf(lv.w + rv.w, 0.f));
      *(u16x4*)(hb + (p * 512 + ((lane * 8) ^ ((p & 7) << 4)))) = pk;
    }
  }
  __syncthreads();

  const f32x4 zero4 = {0.f, 0.f, 0.f, 0.f};

  // ---- Layer A (swapped operands): accA[mt=u-frag 0..3][nt=pair-frag 0..7]
  {
    f32x4 accA[4][8];
    #pragma unroll
    for (int mt = 0; mt < 4; ++mt)
      #pragma unroll
      for (int nt = 0; nt < 8; ++nt) accA[mt][nt] = zero4;
    const bf16x8* wb = (const bf16x8*)Wf;            // layer 0 fragments
    __builtin_amdgcn_s_setprio(1);
    #pragma unroll
    for (int kk = 0; kk < 8; ++kk) {
      bf16x8 wfrag[4];
      #pragma unroll
      for (int mt = 0; mt < 4; ++mt)
        wfrag[mt] = wb[(kk * 16 + wave * 4 + mt) * 64 + lane];
      #pragma unroll
      for (int nt = 0; nt < 8; ++nt) {
        const int prow = nt * 16 + r;
        const bf16x8 hfrag = *(const bf16x8*)(
            hb + (prow * 512 + ((kk * 64 + g * 16) ^ ((r & 7) << 4))));
        #pragma unroll
        for (int mt = 0; mt < 4; ++mt)
          accA[mt][nt] = __builtin_amdgcn_mfma_f32_16x16x32_bf16(
              wfrag[mt], hfrag, accA[mt][nt], 0, 0, 0);
      }
    }
    __builtin_amdgcn_s_setprio(0);
    __syncthreads();  // all reads of h done -> safe to overwrite

    // ---- h' = relu(accA + b1): lane holds u = wave*64+mt*16+g*4+reg,
    // pair = nt*16+r  ->  4 consecutive u -> one b64 write per fragment.
    float4 bias4[4];
    #pragma unroll
    for (int mt = 0; mt < 4; ++mt)
      bias4[mt] = *(const float4*)(biasg + wave * 64 + mt * 16 + g * 4);
    #pragma unroll
    for (int nt = 0; nt < 8; ++nt) {
      const int prow = nt * 16 + r;
      const int swz = (r & 7) << 4;
      #pragma unroll
      for (int mt = 0; mt < 4; ++mt) {
        u16x4 pk;
        pk[0] = f2bf(fmaxf(accA[mt][nt][0] + bias4[mt].x, 0.f));
        pk[1] = f2bf(fmaxf(accA[mt][nt][1] + bias4[mt].y, 0.f));
        pk[2] = f2bf(fmaxf(accA[mt][nt][2] + bias4[mt].z, 0.f));
        pk[3] = f2bf(fmaxf(accA[mt][nt][3] + bias4[mt].w, 0.f));
        const int cb = wave * 128 + mt * 32 + g * 8;
        *(u16x4*)(hb + (prow * 512 + (cb ^ swz))) = pk;
      }
    }
  }
  __syncthreads();

  // ---- Layer B (original operand order): h' -> relu -> column sums -> S
  {
    f32x4 acc[8][4];
    #pragma unroll
    for (int mt = 0; mt < 8; ++mt)
      #pragma unroll
      for (int nt = 0; nt < 4; ++nt) acc[mt][nt] = zero4;
    const bf16x8* wb = (const bf16x8*)(Wf + 65536);  // layer 1 fragments
    __builtin_amdgcn_s_setprio(1);
    #pragma unroll
    for (int kk = 0; kk < 8; ++kk) {
      bf16x8 bfrag[4];
      #pragma unroll
      for (int nt = 0; nt < 4; ++nt)
        bfrag[nt] = wb[(kk * 16 + wave * 4 + nt) * 64 + lane];
      #pragma unroll
      for (int mt = 0; mt < 8; ++mt) {
        const int row = mt * 16 + r;
        const bf16x8 afrag = *(const bf16x8*)(
            hb + (row * 512 + ((kk * 64 + g * 16) ^ ((r & 7) << 4))));
        #pragma unroll
        for (int nt = 0; nt < 4; ++nt)
          acc[mt][nt] = __builtin_amdgcn_mfma_f32_16x16x32_bf16(
              afrag, bfrag[nt], acc[mt][nt], 0, 0, 0);
      }
    }
    __builtin_amdgcn_s_setprio(0);
    #pragma unroll
    for (int nt = 0; nt < 4; ++nt) {
      const int col = wave * 64 + nt * 16 + r;
      const float bias = biasg[256 + col];
      float cs = 0.f;
      #pragma unroll
      for (int mt = 0; mt < 8; ++mt)
        #pragma unroll
        for (int reg = 0; reg < 4; ++reg)
          cs += fmaxf(acc[mt][nt][reg] + bias, 0.f);
      cs += __shfl_xor(cs, 16, 64);
      cs += __shfl_xor(cs, 32, 64);
      if (lane < 16) atomicAdd(&S[(size_t)b * 256 + col], cs);
    }
  }
}

// ---------------------------------------------------------------------------
// F head: per batch: read S[b], 2x(matvec+ReLU) + final 256->128, K-BLOCKED
// col-major weights (each lane loads float4 along k, coalesced).
// ---------------------------------------------------------------------------
__global__ __launch_bounds__(256) void head_kernel(
    const float* __restrict__ S, const float* __restrict__ fWt,
    const float* __restrict__ fbias, const float* __restrict__ foWt,
    const float* __restrict__ fob, float* __restrict__ out) {
  const int b = blockIdx.x;
  const int u = threadIdx.x;
  __shared__ __align__(16) float h[256];
  h[u] = S[(size_t)b * 256 + u];
  __syncthreads();
  #pragma unroll
  for (int l = 0; l < 2; ++l) {
    const float4* wc = (const float4*)fWt + ((size_t)l * 64) * 256 + u;
    float z = 0.f;
    #pragma unroll 8
    for (int k4 = 0; k4 < 64; ++k4) {
      const float4 wv = wc[(size_t)k4 * 256];
      const float4 hv = *((const float4*)&h[k4 * 4]);
      z += wv.x * hv.x + wv.y * hv.y + wv.z * hv.z + wv.w * hv.w;
    }
    z = fmaxf(z + fbias[l * 256 + u], 0.f);
    __syncthreads();
    h[u] = z;
    __syncthreads();
  }
  if (u < 128) {
    const float4* wc = (const float4*)foWt + u;
    float y = fob[u];
    #pragma unroll 8
    for (int k4 = 0; k4 < 64; ++k4) {
      const float4 wv = wc[(size_t)k4 * 128];
      const float4 hv = *((const float4*)&h[k4 * 4]);
      y += wv.x * hv.x + wv.y * hv.y + wv.z * hv.z + wv.w * hv.w;
    }
    out[(size_t)b * 128 + u] = y;
  }
}

extern "C" void kernel_launch(void* const* d_in, const int* in_sizes, int n_in,
                              void* d_out, int out_size, void* d_ws, size_t ws_size,
                              hipStream_t stream) {
  const float* x      = (const float*)d_in[0];
  const float* gW     = (const float*)d_in[1];
  const float* gb     = (const float*)d_in[2];
  const float* ggamma = (const float*)d_in[3];
  const float* gbeta  = (const float*)d_in[4];
  const float* gmean  = (const float*)d_in[5];
  const float* gvar   = (const float*)d_in[6];
  const float* fW     = (const float*)d_in[7];
  const float* fb     = (const float*)d_in[8];
  const float* fgamma = (const float*)d_in[9];
  const float* fbeta  = (const float*)d_in[10];
  const float* fmean  = (const float*)d_in[11];
  const float* fvar   = (const float*)d_in[12];
  const float* foW    = (const float*)d_in[13];
  const float* fob    = (const float*)d_in[14];

  // workspace layout
  u16* Wf = (u16*)d_ws;                    // 2*65536 bf16, fragment-major
  float* biasg = (float*)(Wf + 2 * 65536); // 512 f32
  float* fbias = biasg + 512;              // 512 f32
  float* fWt  = fbias + 512;               // 2*65536 f32, k-blocked col-major
  float* foWt = fWt + 2 * 65536;           // 256*128 f32, k-blocked col-major
  float* W0Tq = foWt + 256 * 128;          // 256*256 f32, k-blocked col-major
  float* S    = W0Tq + 256 * 256;          // 32*256 f32 (atomic accumulator)
  float* Lfp = S + 32 * 256;               // 32*64*256 f32
  float* Rfp = Lfp + 32 * 64 * 256;        // 32*64*256 f32

  prep0<<<dim3(16), 256, 0, stream>>>(gW, W0Tq);
  prep1<<<dim3(329), 256, 0, stream>>>(x, W0Tq, gW, gb, ggamma, gbeta, gmean,
                                       gvar, fW, fb, fgamma, fbeta, fmean,
                                       fvar, foW, Wf, biasg, fWt, fbias, foWt,
                                       Lfp, Rfp, S);
  rn_main<<<dim3(32, 32), 256, 0, stream>>>(Lfp, Rfp, Wf, biasg, S);
  head_kernel<<<dim3(32), 256, 0, stream>>>(S, fWt, fbias, foWt, fob,
                                            (float*)d_out);
}